// Round 1
// baseline (892.677 us; speedup 1.0000x reference)
//
#include <hip/hip_runtime.h>
#include <hip/hip_bf16.h>

#define SS 2048
#define BB 16
#define DD 512

typedef __attribute__((ext_vector_type(4))) float f32x4;
typedef __attribute__((ext_vector_type(8))) short bf16x8;
typedef __attribute__((ext_vector_type(4))) unsigned short us4;

#define MFMA16(a, b, c) __builtin_amdgcn_mfma_f32_16x16x32_bf16((a), (b), (c), 0, 0, 0)

// fp32 -> bf16 round-to-nearest-even
__device__ __forceinline__ unsigned short f2b(float f) {
    union { float f; unsigned u; } v; v.f = f;
    unsigned r = v.u + 0x7FFFu + ((v.u >> 16) & 1u);
    return (unsigned short)(r >> 16);
}

// LDS fragment load with XOR row-swizzle; rowshift = log2(row bytes)
__device__ __forceinline__ bf16x8 ldfrag(const unsigned short* base, int row, int kelem, int rowshift) {
    int off = (row << rowshift) + (kelem << 1);
    off ^= (row & 7) << 4;
    return *(const bf16x8*)((const char*)base + off);
}

__device__ __forceinline__ void gl16(const void* g, void* l) {
    __builtin_amdgcn_global_load_lds(
        (const __attribute__((address_space(1))) unsigned*)g,
        (__attribute__((address_space(3))) unsigned*)l, 16, 0, 0);
}

// ---------------------------------------------------------------------------
// K1: projection GEMM.  out[b][s][n] (or transposed out[b][n][s]) =
//     bf16( seq[s][b][:] . W[n][:] + bias[n] )
// Tile 128x128, BK=64, 4 waves as 2x2 of 64x64.
// ---------------------------------------------------------------------------
__global__ __launch_bounds__(256, 2) void k_proj(
        const float* __restrict__ X, const float* __restrict__ W,
        const float* __restrict__ bias, unsigned short* __restrict__ out,
        int transposed)
{
    __shared__ unsigned short Xa[128 * 64];  // swizzled, 128B rows
    __shared__ unsigned short Wa[128 * 64];

    const int tid = threadIdx.x;
    const int lane = tid & 63;
    const int w = tid >> 6;
    const int wr = w >> 1, wc = w & 1;
    const int l15 = lane & 15, lg = lane >> 4;
    const int b  = blockIdx.x >> 4;
    const int s0 = (blockIdx.x & 15) * 128;
    const int n0 = blockIdx.y * 128;

    f32x4 acc[4][4];
    #pragma unroll
    for (int m = 0; m < 4; ++m)
        #pragma unroll
        for (int n = 0; n < 4; ++n) acc[m][n] = (f32x4)(0.0f);

    for (int k0 = 0; k0 < DD; k0 += 64) {
        #pragma unroll
        for (int j = 0; j < 8; ++j) {
            int idx = tid * 8 + j;          // 0..2047 float4 slots
            int row = idx >> 4;             // 0..127
            int c4  = idx & 15;             // float4 within row
            f32x4 xv = *(const f32x4*)(X + (size_t)(s0 + row) * (BB * DD) + (size_t)b * DD + k0 + c4 * 4);
            f32x4 wv = *(const f32x4*)(W + (size_t)(n0 + row) * DD + k0 + c4 * 4);
            int off = row * 128 + c4 * 8;
            off ^= (row & 7) << 4;
            us4 xp, wp;
            xp.x = f2b(xv.x); xp.y = f2b(xv.y); xp.z = f2b(xv.z); xp.w = f2b(xv.w);
            wp.x = f2b(wv.x); wp.y = f2b(wv.y); wp.z = f2b(wv.z); wp.w = f2b(wv.w);
            *(us4*)((char*)Xa + off) = xp;
            *(us4*)((char*)Wa + off) = wp;
        }
        __syncthreads();
        #pragma unroll
        for (int kk = 0; kk < 2; ++kk) {
            bf16x8 af[4], bfr[4];
            #pragma unroll
            for (int m = 0; m < 4; ++m) af[m]  = ldfrag(Xa, 64 * wr + 16 * m + l15, kk * 32 + 8 * lg, 7);
            #pragma unroll
            for (int n = 0; n < 4; ++n) bfr[n] = ldfrag(Wa, 64 * wc + 16 * n + l15, kk * 32 + 8 * lg, 7);
            #pragma unroll
            for (int m = 0; m < 4; ++m)
                #pragma unroll
                for (int n = 0; n < 4; ++n)
                    acc[m][n] = MFMA16(af[m], bfr[n], acc[m][n]);
        }
        __syncthreads();
    }

    // epilogue: C row = (l>>4)*4 + reg (A row), col = l&15 (B col)  [m89]
    #pragma unroll
    for (int m = 0; m < 4; ++m) {
        #pragma unroll
        for (int n = 0; n < 4; ++n) {
            int col = n0 + 64 * wc + 16 * n + l15;
            float bia = bias[col];
            #pragma unroll
            for (int r = 0; r < 4; ++r) {
                int rowl = 64 * wr + 16 * m + 4 * lg + r;
                unsigned short bv = f2b(acc[m][n][r] + bia);
                if (!transposed)
                    out[((size_t)b * SS + (s0 + rowl)) * DD + col] = bv;
                else
                    out[((size_t)b * DD + col) * SS + (s0 + rowl)] = bv;
            }
        }
    }
}

// ---------------------------------------------------------------------------
// K2: flash attention.  scores[s][t] = V[s,:].Q[t,:] / sqrt(D); P = softmax_t;
// out[s][d] = sum_t P[s][t] * K[t][d]   (K read from transposed Kbt[d][t]).
// 512 thr = 8 waves = 4 row-groups(32 rows) x 2 col-groups(64 score cols).
// QBLK=128, KVBLK=128, dk=64 staged chunks.  Grid 16 x 16 = 256 = 1 block/CU.
// ---------------------------------------------------------------------------
__global__ __launch_bounds__(512, 2) void k_attn(
        const unsigned short* __restrict__ Vb,
        const unsigned short* __restrict__ Qb,
        const unsigned short* __restrict__ Kbt,
        float* __restrict__ out)
{
    __shared__ unsigned short Va[128 * 64];   // V chunk  [row s][64 k], 128B rows, swz
    __shared__ unsigned short Qa[128 * 64];   // Q chunk  [row t][64 k]
    __shared__ unsigned short Kc[128 * 128];  // keys     [row d][128 t], 256B rows, swz
    __shared__ unsigned short Pb[128 * 128];  // P        [row s][128 t], 256B rows, swz
    __shared__ float red[2][2][128];          // cross-cg softmax exchange

    const int tid = threadIdx.x;
    const int lane = tid & 63;
    const int w = tid >> 6;
    const int rg = w & 3;     // rows 32*rg .. +31
    const int cg = w >> 2;    // score cols 64*cg .. +63
    const int l15 = lane & 15, lg = lane >> 4;
    const int b  = blockIdx.y;
    const int s0 = blockIdx.x * 128;
    const float scale = 0.044194173824159216f;  // 1/sqrt(512)

    f32x4 accv[2][4][4];   // [m][dc][nt] -> out rows 32rg+16m+.., cols 128dc+64cg+16nt+..
    #pragma unroll
    for (int m = 0; m < 2; ++m)
        #pragma unroll
        for (int dc = 0; dc < 4; ++dc)
            #pragma unroll
            for (int nt = 0; nt < 4; ++nt) accv[m][dc][nt] = (f32x4)(0.0f);

    float mstate[2][4], lstate[2][4];
    #pragma unroll
    for (int m = 0; m < 2; ++m)
        #pragma unroll
        for (int ri = 0; ri < 4; ++ri) { mstate[m][ri] = -INFINITY; lstate[m][ri] = 0.0f; }

    const char* vbase = (const char*)(Vb + ((size_t)b * SS + s0) * DD);
    const char* kbase = (const char*)(Kbt + (size_t)b * DD * SS);

    for (int t0 = 0; t0 < SS; t0 += 128) {
        // ---------------- QK^T ----------------
        f32x4 sacc[2][4];
        #pragma unroll
        for (int m = 0; m < 2; ++m)
            #pragma unroll
            for (int nt = 0; nt < 4; ++nt) sacc[m][nt] = (f32x4)(0.0f);

        const char* qbase = (const char*)(Qb + ((size_t)b * SS + t0) * DD);
        for (int dk = 0; dk < 8; ++dk) {
            // stage Va/Qa 16KB each: 16 x 1KB chunks, 8 waves x 2
            #pragma unroll
            for (int j = 0; j < 2; ++j) {
                int x = (j * 8 + w) * 1024 + lane * 16;
                int gx = x ^ (((x >> 7) & 7) << 4);     // inverse-swizzle source
                int row = gx >> 7;
                int cb = gx & 127;
                gl16(vbase + (size_t)row * (DD * 2) + dk * 128 + cb, (char*)Va + x);
                gl16(qbase + (size_t)row * (DD * 2) + dk * 128 + cb, (char*)Qa + x);
            }
            __syncthreads();
            #pragma unroll
            for (int kk = 0; kk < 2; ++kk) {
                bf16x8 a0 = ldfrag(Va, 32 * rg + l15,      kk * 32 + 8 * lg, 7);
                bf16x8 a1 = ldfrag(Va, 32 * rg + 16 + l15, kk * 32 + 8 * lg, 7);
                #pragma unroll
                for (int nt = 0; nt < 4; ++nt) {
                    bf16x8 bq = ldfrag(Qa, 64 * cg + 16 * nt + l15, kk * 32 + 8 * lg, 7);
                    sacc[0][nt] = MFMA16(a0, bq, sacc[0][nt]);
                    sacc[1][nt] = MFMA16(a1, bq, sacc[1][nt]);
                }
            }
            __syncthreads();
        }

        // ---------------- online softmax ----------------
        #pragma unroll
        for (int m = 0; m < 2; ++m)
            #pragma unroll
            for (int nt = 0; nt < 4; ++nt) sacc[m][nt] *= scale;

        float rmax[2][4], alpha[2][4], rsum[2][4];
        #pragma unroll
        for (int m = 0; m < 2; ++m)
            #pragma unroll
            for (int ri = 0; ri < 4; ++ri) {
                float v = fmaxf(fmaxf(sacc[m][0][ri], sacc[m][1][ri]),
                                fmaxf(sacc[m][2][ri], sacc[m][3][ri]));
                #pragma unroll
                for (int d = 1; d < 16; d <<= 1) v = fmaxf(v, __shfl_xor(v, d));
                rmax[m][ri] = v;
                if (l15 == 0) red[0][cg][32 * rg + 16 * m + 4 * lg + ri] = v;
            }
        __syncthreads();
        #pragma unroll
        for (int m = 0; m < 2; ++m)
            #pragma unroll
            for (int ri = 0; ri < 4; ++ri) {
                float other = red[0][cg ^ 1][32 * rg + 16 * m + 4 * lg + ri];
                float mn = fmaxf(mstate[m][ri], fmaxf(rmax[m][ri], other));
                alpha[m][ri] = __expf(mstate[m][ri] - mn);
                mstate[m][ri] = mn;
            }
        #pragma unroll
        for (int m = 0; m < 2; ++m)
            #pragma unroll
            for (int nt = 0; nt < 4; ++nt)
                #pragma unroll
                for (int ri = 0; ri < 4; ++ri)
                    sacc[m][nt][ri] = __expf(sacc[m][nt][ri] - mstate[m][ri]);
        #pragma unroll
        for (int m = 0; m < 2; ++m)
            #pragma unroll
            for (int ri = 0; ri < 4; ++ri) {
                float s = sacc[m][0][ri] + sacc[m][1][ri] + sacc[m][2][ri] + sacc[m][3][ri];
                #pragma unroll
                for (int d = 1; d < 16; d <<= 1) s += __shfl_xor(s, d);
                rsum[m][ri] = s;
                if (l15 == 0) red[1][cg][32 * rg + 16 * m + 4 * lg + ri] = s;
            }
        // write P (bf16) to swizzled LDS
        #pragma unroll
        for (int m = 0; m < 2; ++m)
            #pragma unroll
            for (int nt = 0; nt < 4; ++nt)
                #pragma unroll
                for (int ri = 0; ri < 4; ++ri) {
                    int row = 32 * rg + 16 * m + 4 * lg + ri;
                    int col = 64 * cg + 16 * nt + l15;
                    int off = (row << 8) + (col << 1);
                    off ^= (row & 7) << 4;
                    *(unsigned short*)((char*)Pb + off) = f2b(sacc[m][nt][ri]);
                }
        // rescale accumulators
        #pragma unroll
        for (int m = 0; m < 2; ++m)
            #pragma unroll
            for (int ri = 0; ri < 4; ++ri) lstate[m][ri] *= alpha[m][ri];
        #pragma unroll
        for (int m = 0; m < 2; ++m)
            #pragma unroll
            for (int dc = 0; dc < 4; ++dc)
                #pragma unroll
                for (int nt = 0; nt < 4; ++nt)
                    #pragma unroll
                    for (int ri = 0; ri < 4; ++ri)
                        accv[m][dc][nt][ri] *= alpha[m][ri];
        __syncthreads();
        #pragma unroll
        for (int m = 0; m < 2; ++m)
            #pragma unroll
            for (int ri = 0; ri < 4; ++ri)
                lstate[m][ri] += rsum[m][ri] + red[1][cg ^ 1][32 * rg + 16 * m + 4 * lg + ri];

        // ---------------- PV ----------------
        for (int dc = 0; dc < 4; ++dc) {
            // stage Kc 32KB: 32 x 1KB chunks, 8 waves x 4
            #pragma unroll
            for (int j = 0; j < 4; ++j) {
                int x = (j * 8 + w) * 1024 + lane * 16;
                int gx = x ^ (((x >> 8) & 7) << 4);
                int dr = gx >> 8;        // 0..127
                int cb = gx & 255;       // t byte
                gl16(kbase + ((size_t)(dc * 128 + dr) * SS + t0) * 2 + cb, (char*)Kc + x);
            }
            __syncthreads();
            #pragma unroll
            for (int kk = 0; kk < 4; ++kk) {
                bf16x8 pa0 = ldfrag(Pb, 32 * rg + l15,      kk * 32 + 8 * lg, 8);
                bf16x8 pa1 = ldfrag(Pb, 32 * rg + 16 + l15, kk * 32 + 8 * lg, 8);
                #pragma unroll
                for (int nt = 0; nt < 4; ++nt) {
                    bf16x8 bk = ldfrag(Kc, 64 * cg + 16 * nt + l15, kk * 32 + 8 * lg, 8);
                    accv[0][dc][nt] = MFMA16(pa0, bk, accv[0][dc][nt]);
                    accv[1][dc][nt] = MFMA16(pa1, bk, accv[1][dc][nt]);
                }
            }
            __syncthreads();
        }
    }

    // ---------------- epilogue: out[s][b][d] = acc / l ----------------
    #pragma unroll
    for (int m = 0; m < 2; ++m)
        #pragma unroll
        for (int dc = 0; dc < 4; ++dc)
            #pragma unroll
            for (int nt = 0; nt < 4; ++nt)
                #pragma unroll
                for (int ri = 0; ri < 4; ++ri) {
                    int srow = s0 + 32 * rg + 16 * m + 4 * lg + ri;
                    int d = 128 * dc + 64 * cg + 16 * nt + l15;
                    out[((size_t)srow * BB + b) * DD + d] = accv[m][dc][nt][ri] / lstate[m][ri];
                }
}

extern "C" void kernel_launch(void* const* d_in, const int* in_sizes, int n_in,
                              void* d_out, int out_size, void* d_ws, size_t ws_size,
                              hipStream_t stream) {
    const float* seq = (const float*)d_in[0];
    const float* Wv  = (const float*)d_in[1];
    const float* bv  = (const float*)d_in[2];
    const float* Wq  = (const float*)d_in[3];
    const float* bq  = (const float*)d_in[4];
    const float* Wk  = (const float*)d_in[5];
    const float* bk  = (const float*)d_in[6];
    float* out = (float*)d_out;

    unsigned short* Vb  = (unsigned short*)d_ws;                 // [B][S][D] bf16
    unsigned short* Qb  = Vb + (size_t)BB * SS * DD;             // [B][S][D] bf16
    unsigned short* Kbt = Qb + (size_t)BB * SS * DD;             // [B][D][S] bf16 (transposed)

    dim3 g1(256, 4);
    k_proj<<<g1, 256, 0, stream>>>(seq, Wv, bv, Vb, 0);
    k_proj<<<g1, 256, 0, stream>>>(seq, Wq, bq, Qb, 0);
    k_proj<<<g1, 256, 0, stream>>>(seq, Wk, bk, Kbt, 1);

    dim3 g2(16, 16);
    k_attn<<<g2, 512, 0, stream>>>(Vb, Qb, Kbt, out);
}

// Round 2
// 605.245 us; speedup vs baseline: 1.4749x; 1.4749x over previous
//
#include <hip/hip_runtime.h>
#include <hip/hip_bf16.h>

#define SS 2048
#define BB 16
#define DD 512

typedef __attribute__((ext_vector_type(4))) float f32x4;
typedef __attribute__((ext_vector_type(8))) short bf16x8;
typedef __attribute__((ext_vector_type(4))) unsigned short us4;
typedef unsigned short us;

#define MFMA16(a,b,c) __builtin_amdgcn_mfma_f32_16x16x32_bf16((a),(b),(c),0,0,0)
#define BAR() __builtin_amdgcn_s_barrier()
#define WAITV(n) asm volatile("s_waitcnt vmcnt(" #n ")" ::: "memory")
#define WAITL()  asm volatile("s_waitcnt lgkmcnt(0)" ::: "memory")

__device__ __forceinline__ unsigned short f2b(float f) {
    union { float f; unsigned u; } v; v.f = f;
    unsigned r = v.u + 0x7FFFu + ((v.u >> 16) & 1u);
    return (unsigned short)(r >> 16);
}

// LDS fragment load with XOR row-swizzle; rowshift = log2(row bytes)
__device__ __forceinline__ bf16x8 ldfrag(const us* base, int row, int kelem, int rowshift) {
    int off = (row << rowshift) + (kelem << 1);
    off ^= (row & 7) << 4;
    return *(const bf16x8*)((const char*)base + off);
}

__device__ __forceinline__ void gl16(const void* g, void* l) {
    __builtin_amdgcn_global_load_lds(
        (const __attribute__((address_space(1))) unsigned*)g,
        (__attribute__((address_space(3))) unsigned*)l, 16, 0, 0);
}

// ---------------------------------------------------------------------------
// Prep: seq [S][B][D] fp32 -> Xb [B][S][D] bf16 and Xbt [B][D][S] bf16.
// 64x64 tiles, LDS transpose with d-row XOR swizzle.
// ---------------------------------------------------------------------------
__global__ __launch_bounds__(256) void k_prep_x(const float* __restrict__ seq,
        us* __restrict__ Xb, us* __restrict__ Xbt) {
    __shared__ __align__(16) char L[64 * 128];
    const int tid = threadIdx.x;
    const int d0 = blockIdx.x * 64, s0 = blockIdx.y * 64, b = blockIdx.z;
    {
        int r = tid >> 2, seg = (tid & 3) * 16;
        const float* src = seq + (size_t)(s0 + r) * (BB * DD) + (size_t)b * DD + d0 + seg;
        __align__(16) us vals[16];
        #pragma unroll
        for (int q = 0; q < 4; ++q) {
            f32x4 v = *(const f32x4*)(src + q * 4);
            vals[q*4+0] = f2b(v.x); vals[q*4+1] = f2b(v.y);
            vals[q*4+2] = f2b(v.z); vals[q*4+3] = f2b(v.w);
        }
        us* xo = Xb + ((size_t)b * SS + s0 + r) * DD + d0 + seg;
        *(bf16x8*)xo       = *(bf16x8*)&vals[0];
        *(bf16x8*)(xo + 8) = *(bf16x8*)&vals[8];
        #pragma unroll
        for (int j = 0; j < 16; ++j) {
            int d = seg + j;
            int addr = (d * 128 + r * 2) ^ ((d & 7) << 4);
            *(us*)(L + addr) = vals[j];
        }
    }
    __syncthreads();
    {
        int d = tid >> 2, sseg = (tid & 3) * 16;
        int c = (d & 7) << 4;
        int base = d * 128 + sseg * 2;
        bf16x8 h0 = *(bf16x8*)(L + (base ^ c));
        bf16x8 h1 = *(bf16x8*)(L + ((base + 16) ^ c));
        us* o = Xbt + ((size_t)b * DD + d0 + d) * SS + s0 + sseg;
        *(bf16x8*)o       = h0;
        *(bf16x8*)(o + 8) = h1;
    }
}

// ---------------------------------------------------------------------------
// Gt[p][i] = (1/sqrt(D)) * sum_a Wv[a,i] * Wq[a,p]   (bf16 out, fp32 math)
// ---------------------------------------------------------------------------
__global__ __launch_bounds__(256) void k_prepG(const float* __restrict__ Wv,
        const float* __restrict__ Wq, us* __restrict__ Gt) {
    __shared__ float Sq[32][64], Sv[32][64];
    const int tid = threadIdx.x;
    const int p0 = blockIdx.x * 64, i0 = blockIdx.y * 64;
    const int tp = tid & 15, ti = tid >> 4;
    float acc[4][4] = {};
    for (int a0 = 0; a0 < DD; a0 += 32) {
        #pragma unroll
        for (int j = 0; j < 2; ++j) {
            int slot = tid + j * 256;
            int row = slot >> 4, c4 = (slot & 15) * 4;
            *(f32x4*)&Sq[row][c4] = *(const f32x4*)(Wq + (size_t)(a0 + row) * DD + p0 + c4);
            *(f32x4*)&Sv[row][c4] = *(const f32x4*)(Wv + (size_t)(a0 + row) * DD + i0 + c4);
        }
        __syncthreads();
        for (int a = 0; a < 32; ++a) {
            f32x4 q = *(f32x4*)&Sq[a][tp * 4];
            f32x4 v = *(f32x4*)&Sv[a][ti * 4];
            #pragma unroll
            for (int x = 0; x < 4; ++x)
                #pragma unroll
                for (int y = 0; y < 4; ++y)
                    acc[x][y] += q[x] * v[y];
        }
        __syncthreads();
    }
    const float sc = 0.044194173824159216f;
    #pragma unroll
    for (int x = 0; x < 4; ++x)
        #pragma unroll
        for (int y = 0; y < 4; ++y)
            Gt[(size_t)(p0 + tp * 4 + x) * DD + i0 + ti * 4 + y] = f2b(acc[x][y] * sc);
}

// u[p] = (1/sqrt(D)) * sum_a bv[a] * Wq[a,p]
__global__ __launch_bounds__(512) void k_prepU(const float* __restrict__ Wq,
        const float* __restrict__ bv, float* __restrict__ u) {
    int p = threadIdx.x;
    float s = 0.f;
    for (int a0 = 0; a0 < DD; a0 += 8) {
        #pragma unroll
        for (int j = 0; j < 8; ++j)
            s += bv[a0 + j] * Wq[(size_t)(a0 + j) * DD + p];
    }
    u[p] = s * 0.044194173824159216f;
}

__global__ void k_prepW(const float* __restrict__ Wk, us* __restrict__ Wkb) {
    int i = (blockIdx.x * 256 + threadIdx.x) * 4;
    f32x4 v = *(const f32x4*)(Wk + i);
    us4 o; o.x = f2b(v.x); o.y = f2b(v.y); o.z = f2b(v.z); o.w = f2b(v.w);
    *(us4*)(Wkb + i) = o;
}

// ---------------------------------------------------------------------------
// Shared bf16 GEMM: C[row,n] = sum_k A[row,k]*Bm[n,k] + bias[n]
// A rows: [B][S][D] layout (b from grid). 128x128 tile, BK=64, dbuf +
// counted vmcnt + raw barriers.  OUTMODE 0: bf16 out [B][S][D];
// OUTMODE 1: fp32 out at [(s*BB+b)*DD].
// ---------------------------------------------------------------------------
template<int OUTMODE>
__global__ __launch_bounds__(256, 2) void k_gemm(
        const us* __restrict__ A, const us* __restrict__ Bm,
        const float* __restrict__ bias, void* __restrict__ outp) {
    __shared__ __align__(16) us As[2][128 * 64];
    __shared__ __align__(16) us Bs[2][128 * 64];
    const int tid = threadIdx.x;
    const int lane = tid & 63;
    const int w = tid >> 6;
    const int wr = w >> 1, wc = w & 1;
    const int l15 = lane & 15, lg = lane >> 4;
    const int b = blockIdx.x >> 4;
    const int s0 = (blockIdx.x & 15) * 128;
    const int n0 = blockIdx.y * 128;
    const char* abase = (const char*)(A + ((size_t)b * SS + s0) * DD);
    const char* bbase = (const char*)Bm + (size_t)n0 * 1024;

    f32x4 acc[4][4];
    #pragma unroll
    for (int m = 0; m < 4; ++m)
        #pragma unroll
        for (int n = 0; n < 4; ++n) acc[m][n] = (f32x4)(0.0f);

    auto stage = [&](int db, int p) {
        #pragma unroll
        for (int j = 0; j < 4; ++j) {
            int x = (tid + j * 256) * 16;
            int gx = x ^ (((x >> 7) & 7) << 4);
            int row = gx >> 7, col = gx & 127;
            gl16(abase + (size_t)row * 1024 + p * 128 + col, (char*)As[db] + x);
            gl16(bbase + (size_t)row * 1024 + p * 128 + col, (char*)Bs[db] + x);
        }
    };

    stage(0, 0);
    for (int p = 0; p < 8; ++p) {
        if (p < 7) { stage((p + 1) & 1, p + 1); WAITV(8); }
        else       { WAITV(0); }
        BAR();
        const us* Ac = As[p & 1]; const us* Bc = Bs[p & 1];
        #pragma unroll
        for (int kk = 0; kk < 2; ++kk) {
            bf16x8 af[4], bfr[4];
            #pragma unroll
            for (int m = 0; m < 4; ++m) af[m]  = ldfrag(Ac, 64 * wr + 16 * m + l15, kk * 32 + 8 * lg, 7);
            #pragma unroll
            for (int n = 0; n < 4; ++n) bfr[n] = ldfrag(Bc, 64 * wc + 16 * n + l15, kk * 32 + 8 * lg, 7);
            #pragma unroll
            for (int m = 0; m < 4; ++m)
                #pragma unroll
                for (int n = 0; n < 4; ++n)
                    acc[m][n] = MFMA16(af[m], bfr[n], acc[m][n]);
        }
        BAR();
    }

    #pragma unroll
    for (int m = 0; m < 4; ++m) {
        #pragma unroll
        for (int n = 0; n < 4; ++n) {
            int col = n0 + 64 * wc + 16 * n + l15;
            float bia = bias[col];
            #pragma unroll
            for (int r = 0; r < 4; ++r) {
                int row = s0 + 64 * wr + 16 * m + 4 * lg + r;
                float v = acc[m][n][r] + bia;
                if (OUTMODE == 0)
                    ((us*)outp)[((size_t)b * SS + row) * DD + col] = f2b(v);
                else
                    ((float*)outp)[((size_t)row * BB + b) * DD + col] = v;
            }
        }
    }
}

// ---------------------------------------------------------------------------
// Flash attention on folded operands:
//   scores[s,t] = Vt[s,:] . X[t,:]          (already scaled by 1/sqrt(D))
//   P = softmax_t ;  O'[s,e] = sum_t P[s,t] X[t,e]  (Xbt = X^T per batch)
// O' (bf16) overwrites the Vt region in-place (own s-rows only).
// 512 thr = 8 waves = 4 row-groups x 2 col-groups. QBLK=128, KVBLK=128.
// Pipelined: raw barriers + counted vmcnt, cross-phase prefetch.
// ---------------------------------------------------------------------------
__global__ __launch_bounds__(512, 2) void k_attn(
        const us* __restrict__ Vtb, const us* __restrict__ Xb,
        const us* __restrict__ Xbt, us* __restrict__ Ob) {
    __shared__ __align__(16) us VT[2][128 * 64];
    __shared__ __align__(16) us XA[2][128 * 64];
    __shared__ __align__(16) us XT[2][64 * 128];
    __shared__ __align__(16) us Pb[128 * 128];
    __shared__ float red[2][2][128];

    const int tid = threadIdx.x;
    const int lane = tid & 63;
    const int w = tid >> 6;
    const int rg = w & 3;
    const int cg = w >> 2;
    const int l15 = lane & 15, lg = lane >> 4;

    // XCD swizzle: all 16 s-tiles of a batch land on one XCD (2 batches/XCD)
    const int wg = blockIdx.x;
    const int b  = ((wg & 7) << 1) | ((wg >> 3) & 1);
    const int s0 = ((wg >> 4) & 15) * 128;

    const char* vbase  = (const char*)(Vtb + ((size_t)b * SS + s0) * DD);
    const char* xabase = (const char*)(Xb  + (size_t)b * SS * DD);
    const char* xtbase = (const char*)(Xbt + (size_t)b * DD * SS);

    f32x4 accv[2][8][2];
    #pragma unroll
    for (int m = 0; m < 2; ++m)
        #pragma unroll
        for (int ph = 0; ph < 8; ++ph)
            #pragma unroll
            for (int nt = 0; nt < 2; ++nt) accv[m][ph][nt] = (f32x4)(0.0f);

    float mstate[2][4], lstate[2][4];
    #pragma unroll
    for (int m = 0; m < 2; ++m)
        #pragma unroll
        for (int ri = 0; ri < 4; ++ri) { mstate[m][ri] = -INFINITY; lstate[m][ri] = 0.0f; }

    auto stage_qk = [&](int db, int dkk, int tt0) {
        #pragma unroll
        for (int j = 0; j < 2; ++j) {
            int x = (tid + j * 512) * 16;
            int gx = x ^ (((x >> 7) & 7) << 4);
            int row = gx >> 7, col = gx & 127;
            gl16(vbase  + (size_t)row * 1024 + dkk * 128 + col, (char*)VT[db] + x);
            gl16(xabase + (size_t)(tt0 + row) * 1024 + dkk * 128 + col, (char*)XA[db] + x);
        }
    };
    auto stage_xt = [&](int db, int dph, int tt0) {
        #pragma unroll
        for (int j = 0; j < 2; ++j) {
            int x = (tid + j * 512) * 16;
            int gx = x ^ (((x >> 8) & 7) << 4);
            int row = gx >> 8, col = gx & 255;
            gl16(xtbase + (size_t)(dph * 64 + row) * (SS * 2) + (size_t)tt0 * 2 + col,
                 (char*)XT[db] + x);
        }
    };

    stage_qk(0, 0, 0);

    for (int t0 = 0; t0 < SS; t0 += 128) {
        const int t0n = (t0 + 128) & (SS - 1);
        f32x4 sacc[2][4];
        #pragma unroll
        for (int m = 0; m < 2; ++m)
            #pragma unroll
            for (int nt = 0; nt < 4; ++nt) sacc[m][nt] = (f32x4)(0.0f);

        // ---------------- QK^T: 8 pipelined dk-phases ----------------
        #pragma unroll
        for (int p = 0; p < 8; ++p) {
            if (p < 7) { stage_qk((p + 1) & 1, p + 1, t0); WAITV(4); }
            else       { stage_xt(0, 0, t0);               WAITV(2); }
            BAR();
            const us* Vc = VT[p & 1]; const us* Xc = XA[p & 1];
            #pragma unroll
            for (int kk = 0; kk < 2; ++kk) {
                bf16x8 a0 = ldfrag(Vc, 32 * rg + l15,      kk * 32 + 8 * lg, 7);
                bf16x8 a1 = ldfrag(Vc, 32 * rg + 16 + l15, kk * 32 + 8 * lg, 7);
                #pragma unroll
                for (int nt = 0; nt < 4; ++nt) {
                    bf16x8 bq = ldfrag(Xc, 64 * cg + 16 * nt + l15, kk * 32 + 8 * lg, 7);
                    sacc[0][nt] = MFMA16(a0, bq, sacc[0][nt]);
                    sacc[1][nt] = MFMA16(a1, bq, sacc[1][nt]);
                }
            }
            BAR();
        }

        // ---------------- online softmax (scores pre-scaled) ----------------
        stage_xt(1, 1, t0);   // prefetch PV chunk 1 under the softmax
        float rmax[2][4], alpha[2][4], rsum[2][4];
        #pragma unroll
        for (int m = 0; m < 2; ++m)
            #pragma unroll
            for (int ri = 0; ri < 4; ++ri) {
                float v = fmaxf(fmaxf(sacc[m][0][ri], sacc[m][1][ri]),
                                fmaxf(sacc[m][2][ri], sacc[m][3][ri]));
                #pragma unroll
                for (int d = 1; d < 16; d <<= 1) v = fmaxf(v, __shfl_xor(v, d));
                rmax[m][ri] = v;
                if (l15 == 0) red[0][cg][32 * rg + 16 * m + 4 * lg + ri] = v;
            }
        WAITL(); BAR();
        #pragma unroll
        for (int m = 0; m < 2; ++m)
            #pragma unroll
            for (int ri = 0; ri < 4; ++ri) {
                float other = red[0][cg ^ 1][32 * rg + 16 * m + 4 * lg + ri];
                float mn = fmaxf(mstate[m][ri], fmaxf(rmax[m][ri], other));
                alpha[m][ri] = __expf(mstate[m][ri] - mn);
                mstate[m][ri] = mn;
            }
        #pragma unroll
        for (int m = 0; m < 2; ++m)
            #pragma unroll
            for (int nt = 0; nt < 4; ++nt)
                #pragma unroll
                for (int ri = 0; ri < 4; ++ri)
                    sacc[m][nt][ri] = __expf(sacc[m][nt][ri] - mstate[m][ri]);
        #pragma unroll
        for (int m = 0; m < 2; ++m)
            #pragma unroll
            for (int ri = 0; ri < 4; ++ri) {
                float s = sacc[m][0][ri] + sacc[m][1][ri] + sacc[m][2][ri] + sacc[m][3][ri];
                #pragma unroll
                for (int d = 1; d < 16; d <<= 1) s += __shfl_xor(s, d);
                rsum[m][ri] = s;
                if (l15 == 0) red[1][cg][32 * rg + 16 * m + 4 * lg + ri] = s;
            }
        // write P (bf16) to swizzled LDS
        #pragma unroll
        for (int m = 0; m < 2; ++m)
            #pragma unroll
            for (int nt = 0; nt < 4; ++nt)
                #pragma unroll
                for (int ri = 0; ri < 4; ++ri) {
                    int row = 32 * rg + 16 * m + 4 * lg + ri;
                    int col = 64 * cg + 16 * nt + l15;
                    int off = (row << 8) + (col << 1);
                    off ^= (row & 7) << 4;
                    *(us*)((char*)Pb + off) = f2b(sacc[m][nt][ri]);
                }
        // rescale state + accumulators
        #pragma unroll
        for (int m = 0; m < 2; ++m)
            #pragma unroll
            for (int ri = 0; ri < 4; ++ri) lstate[m][ri] *= alpha[m][ri];
        #pragma unroll
        for (int m = 0; m < 2; ++m)
            #pragma unroll
            for (int ph = 0; ph < 8; ++ph)
                #pragma unroll
                for (int nt = 0; nt < 2; ++nt)
                    #pragma unroll
                    for (int ri = 0; ri < 4; ++ri)
                        accv[m][ph][nt][ri] *= alpha[m][ri];
        WAITL(); BAR();
        #pragma unroll
        for (int m = 0; m < 2; ++m)
            #pragma unroll
            for (int ri = 0; ri < 4; ++ri)
                lstate[m][ri] += rsum[m][ri] + red[1][cg ^ 1][32 * rg + 16 * m + 4 * lg + ri];

        // ---------------- PV: 8 pipelined d-phases ----------------
        #pragma unroll
        for (int ph = 0; ph < 8; ++ph) {
            if (ph == 6)      { stage_qk(0, 0, t0n); WAITV(6); }
            else if (ph == 7) { WAITV(4); }
            else              { WAITV(2); }
            BAR();
            const us* Tc = XT[ph & 1];
            #pragma unroll
            for (int kk = 0; kk < 4; ++kk) {
                bf16x8 pa0 = ldfrag(Pb, 32 * rg + l15,      kk * 32 + 8 * lg, 8);
                bf16x8 pa1 = ldfrag(Pb, 32 * rg + 16 + l15, kk * 32 + 8 * lg, 8);
                #pragma unroll
                for (int nt = 0; nt < 2; ++nt) {
                    bf16x8 bx = ldfrag(Tc, 32 * cg + 16 * nt + l15, kk * 32 + 8 * lg, 8);
                    accv[0][ph][nt] = MFMA16(pa0, bx, accv[0][ph][nt]);
                    accv[1][ph][nt] = MFMA16(pa1, bx, accv[1][ph][nt]);
                }
            }
            BAR();
            if (ph < 6) stage_xt(ph & 1, ph + 2, t0);  // refill buffer just consumed
        }
    }

    // ---------------- epilogue: O' = acc / l  -> bf16, overwrite Vt rows ----
    us* orow = Ob + ((size_t)b * SS + s0) * DD;
    #pragma unroll
    for (int m = 0; m < 2; ++m)
        #pragma unroll
        for (int ph = 0; ph < 8; ++ph)
            #pragma unroll
            for (int nt = 0; nt < 2; ++nt)
                #pragma unroll
                for (int ri = 0; ri < 4; ++ri) {
                    int row = 32 * rg + 16 * m + 4 * lg + ri;
                    int e = 64 * ph + 32 * cg + 16 * nt + l15;
                    orow[(size_t)row * DD + e] = f2b(accv[m][ph][nt][ri] / lstate[m][ri]);
                }
}

extern "C" void kernel_launch(void* const* d_in, const int* in_sizes, int n_in,
                              void* d_out, int out_size, void* d_ws, size_t ws_size,
                              hipStream_t stream) {
    const float* seq = (const float*)d_in[0];
    const float* Wv  = (const float*)d_in[1];
    const float* bv  = (const float*)d_in[2];
    const float* Wq  = (const float*)d_in[3];
    // d_in[4] = bq: folds into a softmax-row-constant -> unused
    const float* Wk  = (const float*)d_in[5];
    const float* bk  = (const float*)d_in[6];

    char* ws = (char*)d_ws;
    us*    Xb  = (us*)ws;                                  // [B][S][D] bf16, 32MB
    us*    Xbt = (us*)(ws + (size_t)33554432);             // [B][D][S] bf16, 32MB
    us*    Vtb = (us*)(ws + (size_t)67108864);             // [B][S][D] bf16, 32MB (reused as O')
    us*    Gt  = (us*)(ws + (size_t)100663296);            // [D][D] bf16
    us*    Wkb = (us*)(ws + (size_t)101187584);            // [D][D] bf16
    float* u   = (float*)(ws + (size_t)101711872);         // [D] fp32

    k_prep_x<<<dim3(8, 32, 16), 256, 0, stream>>>(seq, Xb, Xbt);
    k_prepG<<<dim3(8, 8), 256, 0, stream>>>(Wv, Wq, Gt);
    k_prepU<<<1, 512, 0, stream>>>(Wq, bv, u);
    k_prepW<<<256, 256, 0, stream>>>(Wk, Wkb);

    k_gemm<0><<<dim3(256, 4), 256, 0, stream>>>(Xb, Gt, u, (void*)Vtb);   // Vt = X*G + u
    k_attn<<<256, 512, 0, stream>>>(Vtb, Xb, Xbt, Vtb);                   // O' over Vt
    k_gemm<1><<<dim3(256, 4), 256, 0, stream>>>(Vtb, Wkb, bk, d_out);     // out = O'*Wk^T + bk
}

// Round 3
// 403.098 us; speedup vs baseline: 2.2145x; 1.5015x over previous
//
#include <hip/hip_runtime.h>
#include <hip/hip_bf16.h>

#define SS 2048
#define BB 16
#define DD 512

typedef __attribute__((ext_vector_type(4))) float f32x4;
typedef __attribute__((ext_vector_type(8))) short bf16x8;
typedef __attribute__((ext_vector_type(4))) unsigned short us4;
typedef unsigned short us;

#define MFMA16(a,b,c) __builtin_amdgcn_mfma_f32_16x16x32_bf16((a),(b),(c),0,0,0)
#define BAR() __builtin_amdgcn_s_barrier()
#define WAITV(n) asm volatile("s_waitcnt vmcnt(" #n ")" ::: "memory")
#define WAITL()  asm volatile("s_waitcnt lgkmcnt(0)" ::: "memory")

__device__ __forceinline__ unsigned short f2b(float f) {
    union { float f; unsigned u; } v; v.f = f;
    unsigned r = v.u + 0x7FFFu + ((v.u >> 16) & 1u);
    return (unsigned short)(r >> 16);
}

// LDS fragment load with XOR row-swizzle; rowshift = log2(row bytes)
__device__ __forceinline__ bf16x8 ldfrag(const us* base, int row, int kelem, int rowshift) {
    int off = (row << rowshift) + (kelem << 1);
    off ^= (row & 7) << 4;
    return *(const bf16x8*)((const char*)base + off);
}

__device__ __forceinline__ void gl16(const void* g, void* l) {
    __builtin_amdgcn_global_load_lds(
        (const __attribute__((address_space(1))) unsigned*)g,
        (__attribute__((address_space(3))) unsigned*)l, 16, 0, 0);
}

// ---------------------------------------------------------------------------
// Prep: seq [S][B][D] fp32 -> Xb [B][S][D] bf16 and Xbt [B][D][S] bf16.
// ---------------------------------------------------------------------------
__global__ __launch_bounds__(256) void k_prep_x(const float* __restrict__ seq,
        us* __restrict__ Xb, us* __restrict__ Xbt) {
    __shared__ __align__(16) char L[64 * 128];
    const int tid = threadIdx.x;
    const int d0 = blockIdx.x * 64, s0 = blockIdx.y * 64, b = blockIdx.z;
    {
        int r = tid >> 2, seg = (tid & 3) * 16;
        const float* src = seq + (size_t)(s0 + r) * (BB * DD) + (size_t)b * DD + d0 + seg;
        __align__(16) us vals[16];
        #pragma unroll
        for (int q = 0; q < 4; ++q) {
            f32x4 v = *(const f32x4*)(src + q * 4);
            vals[q*4+0] = f2b(v.x); vals[q*4+1] = f2b(v.y);
            vals[q*4+2] = f2b(v.z); vals[q*4+3] = f2b(v.w);
        }
        us* xo = Xb + ((size_t)b * SS + s0 + r) * DD + d0 + seg;
        *(bf16x8*)xo       = *(bf16x8*)&vals[0];
        *(bf16x8*)(xo + 8) = *(bf16x8*)&vals[8];
        #pragma unroll
        for (int j = 0; j < 16; ++j) {
            int d = seg + j;
            int addr = (d * 128 + r * 2) ^ ((d & 7) << 4);
            *(us*)(L + addr) = vals[j];
        }
    }
    __syncthreads();
    {
        int d = tid >> 2, sseg = (tid & 3) * 16;
        int c = (d & 7) << 4;
        int base = d * 128 + sseg * 2;
        bf16x8 h0 = *(bf16x8*)(L + (base ^ c));
        bf16x8 h1 = *(bf16x8*)(L + ((base + 16) ^ c));
        us* o = Xbt + ((size_t)b * DD + d0 + d) * SS + s0 + sseg;
        *(bf16x8*)o       = h0;
        *(bf16x8*)(o + 8) = h1;
    }
}

// ---------------------------------------------------------------------------
// Gt[p][i] = (1/sqrt(D)) * sum_a Wv[a,i] * Wq[a,p]
// ---------------------------------------------------------------------------
__global__ __launch_bounds__(256) void k_prepG(const float* __restrict__ Wv,
        const float* __restrict__ Wq, us* __restrict__ Gt) {
    __shared__ float Sq[32][64], Sv[32][64];
    const int tid = threadIdx.x;
    const int p0 = blockIdx.x * 64, i0 = blockIdx.y * 64;
    const int tp = tid & 15, ti = tid >> 4;
    float acc[4][4] = {};
    for (int a0 = 0; a0 < DD; a0 += 32) {
        #pragma unroll
        for (int j = 0; j < 2; ++j) {
            int slot = tid + j * 256;
            int row = slot >> 4, c4 = (slot & 15) * 4;
            *(f32x4*)&Sq[row][c4] = *(const f32x4*)(Wq + (size_t)(a0 + row) * DD + p0 + c4);
            *(f32x4*)&Sv[row][c4] = *(const f32x4*)(Wv + (size_t)(a0 + row) * DD + i0 + c4);
        }
        __syncthreads();
        for (int a = 0; a < 32; ++a) {
            f32x4 q = *(f32x4*)&Sq[a][tp * 4];
            f32x4 v = *(f32x4*)&Sv[a][ti * 4];
            #pragma unroll
            for (int x = 0; x < 4; ++x)
                #pragma unroll
                for (int y = 0; y < 4; ++y)
                    acc[x][y] += q[x] * v[y];
        }
        __syncthreads();
    }
    const float sc = 0.044194173824159216f;
    #pragma unroll
    for (int x = 0; x < 4; ++x)
        #pragma unroll
        for (int y = 0; y < 4; ++y)
            Gt[(size_t)(p0 + tp * 4 + x) * DD + i0 + ti * 4 + y] = f2b(acc[x][y] * sc);
}

// u[p] = (1/sqrt(D)) * sum_a bv[a] * Wq[a,p]
__global__ __launch_bounds__(512) void k_prepU(const float* __restrict__ Wq,
        const float* __restrict__ bv, float* __restrict__ u) {
    int p = threadIdx.x;
    float s = 0.f;
    for (int a0 = 0; a0 < DD; a0 += 8) {
        #pragma unroll
        for (int j = 0; j < 8; ++j)
            s += bv[a0 + j] * Wq[(size_t)(a0 + j) * DD + p];
    }
    u[p] = s * 0.044194173824159216f;
}

__global__ void k_prepW(const float* __restrict__ Wk, us* __restrict__ Wkb) {
    int i = (blockIdx.x * 256 + threadIdx.x) * 4;
    f32x4 v = *(const f32x4*)(Wk + i);
    us4 o; o.x = f2b(v.x); o.y = f2b(v.y); o.z = f2b(v.z); o.w = f2b(v.w);
    *(us4*)(Wkb + i) = o;
}

// ---------------------------------------------------------------------------
// bf16 GEMM: C[row,n] = sum_k A[row,k]*Bm[n,k] + bias[n]
// ---------------------------------------------------------------------------
template<int OUTMODE>
__global__ __launch_bounds__(256, 2) void k_gemm(
        const us* __restrict__ A, const us* __restrict__ Bm,
        const float* __restrict__ bias, void* __restrict__ outp) {
    __shared__ __align__(16) us As[2][128 * 64];
    __shared__ __align__(16) us Bs[2][128 * 64];
    const int tid = threadIdx.x;
    const int lane = tid & 63;
    const int w = tid >> 6;
    const int wr = w >> 1, wc = w & 1;
    const int l15 = lane & 15, lg = lane >> 4;
    const int b = blockIdx.x >> 4;
    const int s0 = (blockIdx.x & 15) * 128;
    const int n0 = blockIdx.y * 128;
    const char* abase = (const char*)(A + ((size_t)b * SS + s0) * DD);
    const char* bbase = (const char*)Bm + (size_t)n0 * 1024;

    f32x4 acc[4][4];
    #pragma unroll
    for (int m = 0; m < 4; ++m)
        #pragma unroll
        for (int n = 0; n < 4; ++n) acc[m][n] = (f32x4)(0.0f);

    auto stage = [&](int db, int p) {
        #pragma unroll
        for (int j = 0; j < 4; ++j) {
            int x = (tid + j * 256) * 16;
            int gx = x ^ (((x >> 7) & 7) << 4);
            int row = gx >> 7, col = gx & 127;
            gl16(abase + (size_t)row * 1024 + p * 128 + col, (char*)As[db] + x);
            gl16(bbase + (size_t)row * 1024 + p * 128 + col, (char*)Bs[db] + x);
        }
    };

    stage(0, 0);
    for (int p = 0; p < 8; ++p) {
        if (p < 7) { stage((p + 1) & 1, p + 1); WAITV(8); }
        else       { WAITV(0); }
        BAR();
        const us* Ac = As[p & 1]; const us* Bc = Bs[p & 1];
        __builtin_amdgcn_s_setprio(1);
        #pragma unroll
        for (int kk = 0; kk < 2; ++kk) {
            bf16x8 af[4], bfr[4];
            #pragma unroll
            for (int m = 0; m < 4; ++m) af[m]  = ldfrag(Ac, 64 * wr + 16 * m + l15, kk * 32 + 8 * lg, 7);
            #pragma unroll
            for (int n = 0; n < 4; ++n) bfr[n] = ldfrag(Bc, 64 * wc + 16 * n + l15, kk * 32 + 8 * lg, 7);
            #pragma unroll
            for (int m = 0; m < 4; ++m)
                #pragma unroll
                for (int n = 0; n < 4; ++n)
                    acc[m][n] = MFMA16(af[m], bfr[n], acc[m][n]);
        }
        __builtin_amdgcn_s_setprio(0);
        BAR();
    }

    #pragma unroll
    for (int m = 0; m < 4; ++m) {
        #pragma unroll
        for (int n = 0; n < 4; ++n) {
            int col = n0 + 64 * wc + 16 * n + l15;
            float bia = bias[col];
            #pragma unroll
            for (int r = 0; r < 4; ++r) {
                int row = s0 + 64 * wr + 16 * m + 4 * lg + r;
                float v = acc[m][n][r] + bia;
                if (OUTMODE == 0)
                    ((us*)outp)[((size_t)b * SS + row) * DD + col] = f2b(v);
                else
                    ((float*)outp)[((size_t)row * BB + b) * DD + col] = v;
            }
        }
    }
}

// ---------------------------------------------------------------------------
// Flash attention on folded operands, restructured:
//   QBLK=64 rows/block (512 blocks), 8 waves = 4 rg (16 rows) x 2 cg.
//   Vt tile (the score-row operand) lives in REGISTERS (af[16], 64 VGPR).
//   Unified chunk stream per kv-step: 8 X k-chunks + 8 XT e-chunks, 16KB each,
//   4-buffer rotation, depth-3 prefetch, counted WAITV(6).
// ---------------------------------------------------------------------------
__global__ __launch_bounds__(512, 2) void k_attn(
        const us* __restrict__ Vtb, const us* __restrict__ Xb,
        const us* __restrict__ Xbt, us* __restrict__ Ob) {
    __shared__ __align__(16) us BUFS[4][8192];   // 4 x 16KB rotation
    __shared__ __align__(16) us Pb[64 * 128];    // P tile, 256B rows, swz
    __shared__ float red[2][2][64];

    const int tid = threadIdx.x;
    const int lane = tid & 63;
    const int w = tid >> 6;
    const int rg = w & 3;          // rows 16*rg .. +15
    const int cg = w >> 2;         // QK t-half 64*cg; PV e-sub 32*cg
    const int l15 = lane & 15, lg = lane >> 4;

    // XCD swizzle: XCD (wg%8) gets batches {r, r+8}, all 32 s-tiles each
    const int wg = blockIdx.x;
    const int b  = wg & 15;
    const int s0 = (wg >> 4) * 64;

    const char* vbase  = (const char*)(Vtb + ((size_t)b * SS + s0) * DD);
    const char* xabase = (const char*)(Xb  + (size_t)b * SS * DD);
    const char* xtbase = (const char*)(Xbt + (size_t)b * DD * SS);

    auto issueX = [&](int kc, int tt, char* buf) {   // X k-chunk kc, rows tt..+127
        #pragma unroll
        for (int j = 0; j < 2; ++j) {
            int x = (tid + j * 512) * 16;
            int gx = x ^ (((x >> 7) & 7) << 4);
            int row = gx >> 7, col = gx & 127;
            gl16(xabase + (size_t)(tt + row) * 1024 + kc * 128 + col, buf + x);
        }
    };
    auto issueT = [&](int ec, int tt, char* buf) {   // XT e-chunk ec, t-window tt
        #pragma unroll
        for (int j = 0; j < 2; ++j) {
            int x = (tid + j * 512) * 16;
            int gx = x ^ (((x >> 8) & 7) << 4);
            int row = gx >> 8, col = gx & 255;
            gl16(xtbase + (size_t)(ec * 64 + row) * (SS * 2) + (size_t)tt * 2 + col, buf + x);
        }
    };

    // ---- prologue: Vt tile -> registers (af[i] covers k = 32i..32i+31) ----
    bf16x8 af[16];
    #pragma unroll
    for (int vc = 0; vc < 4; ++vc) {
        #pragma unroll
        for (int j = 0; j < 2; ++j) {
            int x = (tid + j * 512) * 16;
            int gx = x ^ (((x >> 8) & 7) << 4);
            int row = gx >> 8, col = gx & 255;
            gl16(vbase + (size_t)row * 1024 + vc * 256 + col, (char*)BUFS[vc] + x);
        }
    }
    WAITV(0); BAR();
    #pragma unroll
    for (int vc = 0; vc < 4; ++vc)
        #pragma unroll
        for (int kk = 0; kk < 4; ++kk)
            af[vc * 4 + kk] = ldfrag(BUFS[vc], 16 * rg + l15, kk * 32 + 8 * lg, 8);
    WAITL(); BAR();

    issueX(0, 0, (char*)BUFS[0]);
    issueX(1, 0, (char*)BUFS[1]);
    issueX(2, 0, (char*)BUFS[2]);

    f32x4 accv[8][2];
    #pragma unroll
    for (int ph = 0; ph < 8; ++ph)
        #pragma unroll
        for (int nt = 0; nt < 2; ++nt) accv[ph][nt] = (f32x4)(0.0f);
    float mstate[4], lstate[4];
    #pragma unroll
    for (int ri = 0; ri < 4; ++ri) { mstate[ri] = -INFINITY; lstate[ri] = 0.0f; }

    const int idx = 16 * rg + 4 * lg;

    for (int t0 = 0; t0 < SS; t0 += 128) {
        const int t0n = (t0 + 128) & (SS - 1);
        f32x4 sacc[4];
        #pragma unroll
        for (int nt = 0; nt < 4; ++nt) sacc[nt] = (f32x4)(0.0f);

        // -------- QK: 8 phases (k-chunks of 64), af from regs --------
        #pragma unroll
        for (int c = 0; c < 8; ++c) {
            if (c + 3 < 8) issueX(c + 3, t0, (char*)BUFS[(c + 3) & 3]);
            else           issueT(c + 3 - 8, t0, (char*)BUFS[(c + 3) & 3]);
            WAITV(6); BAR();
            const us* bufc = BUFS[c & 3];
            __builtin_amdgcn_s_setprio(1);
            #pragma unroll
            for (int kk = 0; kk < 2; ++kk) {
                #pragma unroll
                for (int nt = 0; nt < 4; ++nt) {
                    bf16x8 bq = ldfrag(bufc, 64 * cg + 16 * nt + l15, kk * 32 + 8 * lg, 7);
                    sacc[nt] = MFMA16(af[2 * c + kk], bq, sacc[nt]);
                }
            }
            __builtin_amdgcn_s_setprio(0);
            BAR();
        }

        // -------- online softmax (scores pre-scaled via Gt) --------
        float rmax[4], alpha[4], rsum[4];
        #pragma unroll
        for (int ri = 0; ri < 4; ++ri) {
            float v = fmaxf(fmaxf(sacc[0][ri], sacc[1][ri]), fmaxf(sacc[2][ri], sacc[3][ri]));
            #pragma unroll
            for (int d = 1; d < 16; d <<= 1) v = fmaxf(v, __shfl_xor(v, d));
            rmax[ri] = v;
            if (l15 == 0) red[0][cg][idx + ri] = v;
        }
        WAITL(); BAR();
        #pragma unroll
        for (int ri = 0; ri < 4; ++ri) {
            float mn = fmaxf(mstate[ri], fmaxf(rmax[ri], red[0][cg ^ 1][idx + ri]));
            alpha[ri] = __expf(mstate[ri] - mn);
            mstate[ri] = mn;
        }
        #pragma unroll
        for (int nt = 0; nt < 4; ++nt)
            #pragma unroll
            for (int ri = 0; ri < 4; ++ri)
                sacc[nt][ri] = __expf(sacc[nt][ri] - mstate[ri]);
        #pragma unroll
        for (int ri = 0; ri < 4; ++ri) {
            float s = sacc[0][ri] + sacc[1][ri] + sacc[2][ri] + sacc[3][ri];
            #pragma unroll
            for (int d = 1; d < 16; d <<= 1) s += __shfl_xor(s, d);
            rsum[ri] = s;
            if (l15 == 0) red[1][cg][idx + ri] = s;
        }
        #pragma unroll
        for (int nt = 0; nt < 4; ++nt)
            #pragma unroll
            for (int ri = 0; ri < 4; ++ri) {
                int row = idx + ri;
                int col = 64 * cg + 16 * nt + l15;
                int off = ((row << 8) + (col << 1)) ^ ((row & 7) << 4);
                *(us*)((char*)Pb + off) = f2b(sacc[nt][ri]);
            }
        #pragma unroll
        for (int ph = 0; ph < 8; ++ph)
            #pragma unroll
            for (int nt = 0; nt < 2; ++nt)
                #pragma unroll
                for (int ri = 0; ri < 4; ++ri)
                    accv[ph][nt][ri] *= alpha[ri];
        #pragma unroll
        for (int ri = 0; ri < 4; ++ri) lstate[ri] *= alpha[ri];
        WAITL(); BAR();
        #pragma unroll
        for (int ri = 0; ri < 4; ++ri)
            lstate[ri] += rsum[ri] + red[1][cg ^ 1][idx + ri];

        // -------- PV: 8 phases (e-chunks of 64) --------
        #pragma unroll
        for (int c = 8; c < 16; ++c) {
            if (c + 3 < 16) issueT(c + 3 - 8, t0, (char*)BUFS[(c + 3) & 3]);
            else            issueX(c + 3 - 16, t0n, (char*)BUFS[(c + 3) & 3]);
            WAITV(6); BAR();
            const us* bufc = BUFS[c & 3];
            const int ph = c - 8;
            __builtin_amdgcn_s_setprio(1);
            #pragma unroll
            for (int kk = 0; kk < 4; ++kk) {
                bf16x8 pa = ldfrag(Pb, 16 * rg + l15, kk * 32 + 8 * lg, 8);
                #pragma unroll
                for (int nt = 0; nt < 2; ++nt) {
                    bf16x8 bx = ldfrag(bufc, 32 * cg + 16 * nt + l15, kk * 32 + 8 * lg, 8);
                    accv[ph][nt] = MFMA16(pa, bx, accv[ph][nt]);
                }
            }
            __builtin_amdgcn_s_setprio(0);
            BAR();
        }
    }

    // -------- epilogue: O' = acc / l -> bf16, overwrite own Vt rows --------
    us* orow = Ob + ((size_t)b * SS + s0) * DD;
    #pragma unroll
    for (int ph = 0; ph < 8; ++ph)
        #pragma unroll
        for (int nt = 0; nt < 2; ++nt)
            #pragma unroll
            for (int ri = 0; ri < 4; ++ri) {
                int row = idx + ri;
                int e = 64 * ph + 32 * cg + 16 * nt + l15;
                orow[(size_t)row * DD + e] = f2b(accv[ph][nt][ri] / lstate[ri]);
            }
}

extern "C" void kernel_launch(void* const* d_in, const int* in_sizes, int n_in,
                              void* d_out, int out_size, void* d_ws, size_t ws_size,
                              hipStream_t stream) {
    const float* seq = (const float*)d_in[0];
    const float* Wv  = (const float*)d_in[1];
    const float* bv  = (const float*)d_in[2];
    const float* Wq  = (const float*)d_in[3];
    // d_in[4] = bq: softmax-row-constant -> unused
    const float* Wk  = (const float*)d_in[5];
    const float* bk  = (const float*)d_in[6];

    char* ws = (char*)d_ws;
    us*    Xb  = (us*)ws;                                  // [B][S][D] bf16, 32MB
    us*    Xbt = (us*)(ws + (size_t)33554432);             // [B][D][S] bf16, 32MB
    us*    Vtb = (us*)(ws + (size_t)67108864);             // [B][S][D] bf16, 32MB (reused as O')
    us*    Gt  = (us*)(ws + (size_t)100663296);            // [D][D] bf16
    us*    Wkb = (us*)(ws + (size_t)101187584);            // [D][D] bf16
    float* u   = (float*)(ws + (size_t)101711872);         // [D] fp32

    k_prep_x<<<dim3(8, 32, 16), 256, 0, stream>>>(seq, Xb, Xbt);
    k_prepG<<<dim3(8, 8), 256, 0, stream>>>(Wv, Wq, Gt);
    k_prepU<<<1, 512, 0, stream>>>(Wq, bv, u);
    k_prepW<<<256, 256, 0, stream>>>(Wk, Wkb);

    k_gemm<0><<<dim3(256, 4), 256, 0, stream>>>(Xb, Gt, u, (void*)Vtb);   // Vt = X*G + u
    k_attn<<<512, 512, 0, stream>>>(Vtb, Xb, Xbt, Vtb);                   // O' over Vt
    k_gemm<1><<<dim3(256, 4), 256, 0, stream>>>(Vtb, Wkb, bk, d_out);     // out = O'*Wk^T + bk
}